// Round 1
// baseline (199.192 us; speedup 1.0000x reference)
//
#include <hip/hip_runtime.h>
#include <hip/hip_bf16.h>

// Problem constants
#define BB    16
#define CREF  256
#define CINC  256
#define COUTC 256
#define KKN   4
#define HH    56
#define WWW   56
#define HIDDEN 65
#define NPIX  3136          // 56*56
#define PPIX  3364          // 58*58 padded
#define TEMP  34.0f

typedef __bf16 bf16x8 __attribute__((ext_vector_type(8)));
typedef float  f32x4  __attribute__((ext_vector_type(4)));

// ---------------- ws layout (bytes) ----------------
// attn   @ 0        : 16*4*4        = 256
// aggb   @ 4096     : 16*256*4      = 16384
// pooled @ 24576    : 16*256*4      = 16384
// aggw   @ 65536    : 16*9*256*256*2 = 18,874,368   [b][tap][cout][cin] bf16
// xpad   @ 19005440 : 16*3364*256*2 = 27,557,888 (+4KB slack for staging overread)
#define WS_ATTN   0
#define WS_AGGB   4096
#define WS_POOL   24576
#define WS_AGGW   65536
#define WS_XPAD   19005440

// ---------- 1. adaptive avg pool: one wave per (b,c) ----------
__global__ void pool_k(const float* __restrict__ ref, float* __restrict__ pooled) {
    int wid = threadIdx.x >> 6, lane = threadIdx.x & 63;
    int gw = blockIdx.x * 4 + wid;            // 0..4095 = b*256+c
    const float4* r4 = reinterpret_cast<const float4*>(ref) + (size_t)gw * 784;
    float s = 0.f;
    for (int i = lane; i < 784; i += 64) {
        float4 v = r4[i];
        s += v.x + v.y + v.z + v.w;
    }
    for (int o = 32; o; o >>= 1) s += __shfl_xor(s, o);
    if (lane == 0) pooled[gw] = s * (1.0f / (float)NPIX);
}

// ---------- 2. attention: fc1+relu, fc2, softmax (1 block) ----------
__global__ void attn_k(const float* __restrict__ pooled, const float* __restrict__ fc1w,
                       const float* __restrict__ fc2w, const float* __restrict__ fc2b,
                       float* __restrict__ attn) {
    __shared__ float sh_h[BB * HIDDEN];
    __shared__ float sh_l[BB * KKN];
    int t = threadIdx.x;
    for (int p = t; p < BB * HIDDEN; p += 256) {
        int b = p / HIDDEN, j = p % HIDDEN;
        float s = 0.f;
        for (int c = 0; c < CREF; ++c) s += pooled[b * CREF + c] * fc1w[j * CREF + c];
        sh_h[p] = fmaxf(s, 0.f);
    }
    __syncthreads();
    if (t < BB * KKN) {
        int b = t >> 2, k = t & 3;
        float s = fc2b[k];
        for (int j = 0; j < HIDDEN; ++j) s += sh_h[b * HIDDEN + j] * fc2w[k * HIDDEN + j];
        sh_l[t] = s / TEMP;
    }
    __syncthreads();
    if (t < BB) {
        float m = -1e30f;
        for (int k = 0; k < KKN; ++k) m = fmaxf(m, sh_l[t * 4 + k]);
        float e[KKN], sum = 0.f;
        for (int k = 0; k < KKN; ++k) { e[k] = expf(sh_l[t * 4 + k] - m); sum += e[k]; }
        for (int k = 0; k < KKN; ++k) attn[t * 4 + k] = e[k] / sum;
    }
}

// ---------- 3. agg bias ----------
__global__ void aggb_k(const float* __restrict__ attn, const float* __restrict__ bias,
                       float* __restrict__ aggb) {
    int b = blockIdx.x, c = threadIdx.x;
    float s = 0.f;
    for (int k = 0; k < KKN; ++k) s += attn[b * 4 + k] * bias[k * COUTC + c];
    aggb[b * COUTC + c] = s;
}

// ---------- 4. blend weights -> bf16 [b][tap][cout][cin] ----------
__global__ void aggw_k(const float* __restrict__ attn, const float* __restrict__ weight,
                       __bf16* __restrict__ aggw) {
    __shared__ float s_attn[64];
    int cout = blockIdx.x, cin = threadIdx.x;
    if (threadIdx.x < 64) s_attn[threadIdx.x] = attn[threadIdx.x];
    __syncthreads();
    int tap0 = blockIdx.y * 3;
    size_t wrow = ((size_t)cout * 256 + cin) * 9;
    for (int dt = 0; dt < 3; ++dt) {
        int tap = tap0 + dt;
        float w0 = weight[0 * 589824 + wrow + tap];
        float w1 = weight[1 * 589824 + wrow + tap];
        float w2 = weight[2 * 589824 + wrow + tap];
        float w3 = weight[3 * 589824 + wrow + tap];
        for (int b = 0; b < BB; ++b) {
            float v = s_attn[b * 4 + 0] * w0 + s_attn[b * 4 + 1] * w1 +
                      s_attn[b * 4 + 2] * w2 + s_attn[b * 4 + 3] * w3;
            aggw[(((size_t)(b * 9 + tap) * 256 + cout) * 256) + cin] = (__bf16)v;
        }
    }
}

// ---------- 5. x -> padded NHWC bf16 (interior, tiled transpose) ----------
__global__ void xpad_int_k(const float* __restrict__ x, __bf16* __restrict__ xpad) {
    __shared__ float tile[64][65];
    int pt = blockIdx.x;      // 0..48 pixel tile (64 px)
    int cg = blockIdx.y;      // 0..3 cin group (64 cins)
    int b  = blockIdx.z;
    int q = threadIdx.x >> 6, l = threadIdx.x & 63;
    // read: coalesced along pixels
    for (int k = 0; k < 16; ++k) {
        int cl = q * 16 + k;
        tile[cl][l] = x[((size_t)(b * 256 + cg * 64 + cl)) * NPIX + pt * 64 + l];
    }
    __syncthreads();
    // write: coalesced along cins
    for (int k = 0; k < 16; ++k) {
        int pl = q * 16 + k;
        int pixel = pt * 64 + pl;
        int h = pixel / 56, w = pixel - h * 56;
        xpad[(((size_t)b * PPIX + (h + 1) * 58 + (w + 1)) * 256) + cg * 64 + l] =
            (__bf16)tile[l][pl];
    }
}

// ---------- 6. xpad border zeros ----------
__global__ void xpad_bor_k(__bf16* __restrict__ xpad) {
    int b = blockIdx.x / 228, i = blockIdx.x % 228;
    int ph, pw;
    if (i < 58)       { ph = 0;        pw = i; }
    else if (i < 116) { ph = 57;       pw = i - 58; }
    else if (i < 172) { ph = i - 115;  pw = 0; }
    else              { ph = i - 171;  pw = 57; }
    xpad[(((size_t)b * PPIX + ph * 58 + pw) * 256) + threadIdx.x] = (__bf16)0.f;
}

// ---------- 7. conv via implicit GEMM (MFMA bf16) ----------
// tile: 128 couts x 112 pixels (2 rows), K-loop: 8 cin-blocks of 32, 9 taps share one staging
// LDS: [cg(4)][row(4)][col(64)][16B] = 16KB, conflict-free consecutive-col reads
__global__ __launch_bounds__(256) void conv_k(const __bf16* __restrict__ xpad,
                                              const __bf16* __restrict__ aggw,
                                              const float* __restrict__ aggb,
                                              float* __restrict__ out) {
    __shared__ __attribute__((aligned(16))) __bf16 lds[8192];   // 16 KB
    const int rp = blockIdx.x;       // 0..27 row-pair
    const int ch = blockIdx.y;       // 0..1 cout half
    const int b  = blockIdx.z;       // 0..15
    const int tid = threadIdx.x;
    const int wid = tid >> 6, lane = tid & 63;
    const int l15 = lane & 15, l4 = lane >> 4;
    const int h0 = rp * 2;
    const int coutb = ch * 128 + wid * 32;

    int boff[7];
#pragma unroll
    for (int nf = 0; nf < 7; ++nf) {
        int p = nf * 16 + l15;
        int r = (p >= 56) ? 1 : 0;
        int c = p - r * 56;
        boff[nf] = l4 * 4096 + r * 1024 + c * 16;   // byte offset in LDS
    }

    f32x4 acc[2][7];
#pragma unroll
    for (int m = 0; m < 2; ++m)
#pragma unroll
        for (int n = 0; n < 7; ++n) acc[m][n] = (f32x4){0.f, 0.f, 0.f, 0.f};

    const char* xb = (const char*)xpad + (size_t)b * PPIX * 512;

    for (int cb8 = 0; cb8 < 8; ++cb8) {
        __syncthreads();  // previous iter done reading LDS
#pragma unroll
        for (int j = 0; j < 4; ++j) {
            int o = (wid * 4 + j) * 1024 + lane * 16;
            int cg  = o >> 12;
            int row = (o >> 10) & 3;
            int col = (o >> 4) & 63;
            const char* src = xb + (size_t)((h0 + row) * 58 + col) * 512 + cb8 * 64 + cg * 16;
            __builtin_amdgcn_global_load_lds(
                (const __attribute__((address_space(1))) void*)src,
                (__attribute__((address_space(3))) void*)((char*)lds + (wid * 4 + j) * 1024),
                16, 0, 0);
        }
        __syncthreads();  // staged (compiler drains vmcnt before barrier)

#pragma unroll
        for (int kh = 0; kh < 3; ++kh) {
#pragma unroll
            for (int kw = 0; kw < 3; ++kw) {
                const int tap = kh * 3 + kw;
                const __bf16* ab = aggw +
                    (((size_t)(b * 9 + tap) * 256 + coutb + l15) * 256 + cb8 * 32 + l4 * 8);
                bf16x8 a0 = *(const bf16x8*)(ab);
                bf16x8 a1 = *(const bf16x8*)(ab + 16 * 256);
#pragma unroll
                for (int nf = 0; nf < 7; ++nf) {
                    bf16x8 bb = *(const bf16x8*)((const char*)lds + boff[nf] + kh * 1024 + kw * 16);
                    acc[0][nf] = __builtin_amdgcn_mfma_f32_16x16x32_bf16(a0, bb, acc[0][nf], 0, 0, 0);
                    acc[1][nf] = __builtin_amdgcn_mfma_f32_16x16x32_bf16(a1, bb, acc[1][nf], 0, 0, 0);
                }
            }
        }
    }

    const int pix0 = rp * 112;
#pragma unroll
    for (int m = 0; m < 2; ++m) {
#pragma unroll
        for (int i = 0; i < 4; ++i) {
            int cout = coutb + m * 16 + l4 * 4 + i;
            float bbv = aggb[b * COUTC + cout];
            float* op = out + ((size_t)(b * COUTC + cout) * NPIX + pix0 + l15);
#pragma unroll
            for (int nf = 0; nf < 7; ++nf) op[nf * 16] = acc[m][nf][i] + bbv;
        }
    }
}

extern "C" void kernel_launch(void* const* d_in, const int* in_sizes, int n_in,
                              void* d_out, int out_size, void* d_ws, size_t ws_size,
                              hipStream_t stream) {
    (void)in_sizes; (void)n_in; (void)out_size; (void)ws_size;
    const float* ref    = (const float*)d_in[0];
    const float* x      = (const float*)d_in[1];
    const float* fc1w   = (const float*)d_in[2];
    const float* fc2w   = (const float*)d_in[3];
    const float* fc2b   = (const float*)d_in[4];
    const float* weight = (const float*)d_in[5];
    const float* bias   = (const float*)d_in[6];
    float* out = (float*)d_out;
    char* ws = (char*)d_ws;

    float*  attn   = (float*)(ws + WS_ATTN);
    float*  aggb   = (float*)(ws + WS_AGGB);
    float*  pooled = (float*)(ws + WS_POOL);
    __bf16* aggw   = (__bf16*)(ws + WS_AGGW);
    __bf16* xpad   = (__bf16*)(ws + WS_XPAD);

    pool_k<<<1024, 256, 0, stream>>>(ref, pooled);
    attn_k<<<1, 256, 0, stream>>>(pooled, fc1w, fc2w, fc2b, attn);
    aggb_k<<<16, 256, 0, stream>>>(attn, bias, aggb);
    aggw_k<<<dim3(256, 3), 256, 0, stream>>>(attn, weight, aggw);
    xpad_int_k<<<dim3(49, 4, 16), 256, 0, stream>>>(x, xpad);
    xpad_bor_k<<<3648, 256, 0, stream>>>(xpad);
    conv_k<<<dim3(28, 2, 16), 256, 0, stream>>>(xpad, aggw, aggb, out);
}

// Round 2
// 151.684 us; speedup vs baseline: 1.3132x; 1.3132x over previous
//
#include <hip/hip_runtime.h>
#include <hip/hip_bf16.h>

// Problem constants
#define BB    16
#define CREF  256
#define CINC  256
#define COUTC 256
#define KKN   4
#define HH    56
#define WWW   56
#define HIDDEN 65
#define NPIX  3136          // 56*56
#define PPIX  3364          // 58*58 padded
#define TEMP  34.0f

typedef __bf16 bf16x8 __attribute__((ext_vector_type(8)));
typedef float  f32x4  __attribute__((ext_vector_type(4)));

// ---------------- ws layout (bytes) ----------------
#define WS_ATTN   0
#define WS_AGGB   4096
#define WS_POOL   24576
#define WS_AGGW   65536      // 16*9*256*256*2 = 18,874,368  [b][tap][cb8][cout][cin32] bf16
#define WS_XPAD   19005440   // 16*3364*256*2 = 27,557,888

// ---------- 1. adaptive avg pool: one wave per (b,c) ----------
__global__ void pool_k(const float* __restrict__ ref, float* __restrict__ pooled) {
    int wid = threadIdx.x >> 6, lane = threadIdx.x & 63;
    int gw = blockIdx.x * 4 + wid;            // 0..4095 = b*256+c
    const float4* r4 = reinterpret_cast<const float4*>(ref) + (size_t)gw * 784;
    float s = 0.f;
    for (int i = lane; i < 784; i += 64) {
        float4 v = r4[i];
        s += v.x + v.y + v.z + v.w;
    }
    for (int o = 32; o; o >>= 1) s += __shfl_xor(s, o);
    if (lane == 0) pooled[gw] = s * (1.0f / (float)NPIX);
}

// ---------- 2. attention ----------
__global__ void attn_k(const float* __restrict__ pooled, const float* __restrict__ fc1w,
                       const float* __restrict__ fc2w, const float* __restrict__ fc2b,
                       float* __restrict__ attn) {
    __shared__ float sh_h[BB * HIDDEN];
    __shared__ float sh_l[BB * KKN];
    int t = threadIdx.x;
    for (int p = t; p < BB * HIDDEN; p += 256) {
        int b = p / HIDDEN, j = p % HIDDEN;
        float s = 0.f;
        for (int c = 0; c < CREF; ++c) s += pooled[b * CREF + c] * fc1w[j * CREF + c];
        sh_h[p] = fmaxf(s, 0.f);
    }
    __syncthreads();
    if (t < BB * KKN) {
        int b = t >> 2, k = t & 3;
        float s = fc2b[k];
        for (int j = 0; j < HIDDEN; ++j) s += sh_h[b * HIDDEN + j] * fc2w[k * HIDDEN + j];
        sh_l[t] = s / TEMP;
    }
    __syncthreads();
    if (t < BB) {
        float m = -1e30f;
        for (int k = 0; k < KKN; ++k) m = fmaxf(m, sh_l[t * 4 + k]);
        float e[KKN], sum = 0.f;
        for (int k = 0; k < KKN; ++k) { e[k] = expf(sh_l[t * 4 + k] - m); sum += e[k]; }
        for (int k = 0; k < KKN; ++k) attn[t * 4 + k] = e[k] / sum;
    }
}

// ---------- 3. agg bias ----------
__global__ void aggb_k(const float* __restrict__ attn, const float* __restrict__ bias,
                       float* __restrict__ aggb) {
    int b = blockIdx.x, c = threadIdx.x;
    float s = 0.f;
    for (int k = 0; k < KKN; ++k) s += attn[b * 4 + k] * bias[k * COUTC + c];
    aggb[b * COUTC + c] = s;
}

// ---------- 4. blend weights -> bf16 [b][tap][cb8][cout][cin32] ----------
// block = cout (256), thread = cin (256). Per-thread reads 36B contiguous x4 banks.
__global__ void aggw_k(const float* __restrict__ attn, const float* __restrict__ weight,
                       __bf16* __restrict__ aggw) {
    __shared__ float s_attn[64];
    int cout = blockIdx.x, cin = threadIdx.x;
    if (threadIdx.x < 64) s_attn[threadIdx.x] = attn[threadIdx.x];
    __syncthreads();
    float w[4][9];
#pragma unroll
    for (int k = 0; k < 4; ++k) {
        const float* wp = weight + ((size_t)(k * 256 + cout) * 256 + cin) * 9;
#pragma unroll
        for (int t = 0; t < 9; ++t) w[k][t] = wp[t];
    }
    int cg = cin >> 5, cr = cin & 31;
    for (int b = 0; b < BB; ++b) {
        float a0 = s_attn[b * 4 + 0], a1 = s_attn[b * 4 + 1];
        float a2 = s_attn[b * 4 + 2], a3 = s_attn[b * 4 + 3];
#pragma unroll
        for (int tap = 0; tap < 9; ++tap) {
            float v = a0 * w[0][tap] + a1 * w[1][tap] + a2 * w[2][tap] + a3 * w[3][tap];
            aggw[(((size_t)((b * 9 + tap) * 8 + cg) * 256 + cout) * 32) + cr] = (__bf16)v;
        }
    }
}

// ---------- 5. x -> padded NHWC bf16 (interior, tiled transpose) ----------
__global__ void xpad_int_k(const float* __restrict__ x, __bf16* __restrict__ xpad) {
    __shared__ float tile[64][65];
    int pt = blockIdx.x;      // 0..48 pixel tile (64 px)
    int cg = blockIdx.y;      // 0..3 cin group (64 cins)
    int b  = blockIdx.z;
    int q = threadIdx.x >> 6, l = threadIdx.x & 63;
    for (int k = 0; k < 16; ++k) {
        int cl = q * 16 + k;
        tile[cl][l] = x[((size_t)(b * 256 + cg * 64 + cl)) * NPIX + pt * 64 + l];
    }
    __syncthreads();
    for (int k = 0; k < 16; ++k) {
        int pl = q * 16 + k;
        int pixel = pt * 64 + pl;
        int h = pixel / 56, w = pixel - h * 56;
        xpad[(((size_t)b * PPIX + (h + 1) * 58 + (w + 1)) * 256) + cg * 64 + l] =
            (__bf16)tile[l][pl];
    }
}

// ---------- 6. xpad border zeros ----------
__global__ void xpad_bor_k(__bf16* __restrict__ xpad) {
    int b = blockIdx.x / 228, i = blockIdx.x % 228;
    int ph, pw;
    if (i < 58)       { ph = 0;        pw = i; }
    else if (i < 116) { ph = 57;       pw = i - 58; }
    else if (i < 172) { ph = i - 115;  pw = 0; }
    else              { ph = i - 171;  pw = 57; }
    xpad[(((size_t)b * PPIX + ph * 58 + pw) * 256) + threadIdx.x] = (__bf16)0.f;
}

// ---------- 7. conv via implicit GEMM (MFMA bf16), 2-phase pipelined ----------
// block: 128 couts x 224 px (4 output rows). wave: 64 couts x 112 px.
// K-loop: 8 cin-blocks of 32 cins, double-buffered LDS staging of 6 input rows.
// LDS buffer layout: [cg(4)][row(6)][col(64)][8cin=16B] = 24KB per buffer.
__global__ __launch_bounds__(256, 2) void conv_k(const __bf16* __restrict__ xpad,
                                                 const __bf16* __restrict__ aggw,
                                                 const float* __restrict__ aggb,
                                                 float* __restrict__ out) {
    __shared__ __attribute__((aligned(16))) __bf16 lds[24576];   // 2 x 24KB
    const int rp = blockIdx.x;       // 0..13 row-quad
    const int ch = blockIdx.y;       // 0..1 cout half
    const int b  = blockIdx.z;       // 0..15
    const int tid = threadIdx.x;
    const int wid = tid >> 6, lane = tid & 63;
    const int l15 = lane & 15, l4 = lane >> 4;
    const int wm = wid & 1, wn = wid >> 1;
    const int h0 = rp * 4;                    // padded top row of this block
    const int coutb = ch * 128 + wm * 64;

    // per-lane B-frag base offsets (bytes within one 24KB buffer)
    int bo[7];
#pragma unroll
    for (int nf = 0; nf < 7; ++nf) {
        int p = nf * 16 + l15;
        int r = (p >= 56) ? 1 : 0;
        int c = p - r * 56;
        bo[nf] = l4 * 6144 + r * 1024 + c * 16;
    }

    f32x4 acc[4][7];
#pragma unroll
    for (int m = 0; m < 4; ++m)
#pragma unroll
        for (int n = 0; n < 7; ++n) acc[m][n] = (f32x4){0.f, 0.f, 0.f, 0.f};

    const char* xb = (const char*)xpad + (size_t)b * PPIX * 512;

    // stage one 32-cin block into buffer `buf`: wave wid handles cg=wid, rows j=0..5
    auto STAGE = [&](int buf, int cb8) {
#pragma unroll
        for (int j = 0; j < 6; ++j) {
            const char* src = xb + (size_t)((h0 + j) * 58 + lane) * 512 + cb8 * 64 + wid * 16;
            __builtin_amdgcn_global_load_lds(
                (const __attribute__((address_space(1))) void*)src,
                (__attribute__((address_space(3))) void*)((char*)lds + buf * 24576 + (wid * 6 + j) * 1024),
                16, 0, 0);
        }
    };

    STAGE(0, 0);
    __syncthreads();                          // drains vmcnt: buf0 ready
    int cur = 0;
    for (int cb8 = 0; cb8 < 8; ++cb8) {
        if (cb8 < 7) STAGE(cur ^ 1, cb8 + 1); // issue next-stage loads first
        const char* lb = (const char*)lds + cur * 24576;
#pragma unroll
        for (int kh = 0; kh < 3; ++kh) {
#pragma unroll
            for (int kw = 0; kw < 3; ++kw) {
                const int tap = kh * 3 + kw;
                const __bf16* ap = aggw +
                    (((size_t)((b * 9 + tap) * 8 + cb8) * 256 + coutb + l15) * 32 + l4 * 8);
                bf16x8 a0 = *(const bf16x8*)(ap);
                bf16x8 a1 = *(const bf16x8*)(ap + 16 * 32);
                bf16x8 a2 = *(const bf16x8*)(ap + 32 * 32);
                bf16x8 a3 = *(const bf16x8*)(ap + 48 * 32);
#pragma unroll
                for (int nf = 0; nf < 7; ++nf) {
                    bf16x8 bb = *(const bf16x8*)(lb + bo[nf] + (wn * 2 + kh) * 1024 + kw * 16);
                    acc[0][nf] = __builtin_amdgcn_mfma_f32_16x16x32_bf16(a0, bb, acc[0][nf], 0, 0, 0);
                    acc[1][nf] = __builtin_amdgcn_mfma_f32_16x16x32_bf16(a1, bb, acc[1][nf], 0, 0, 0);
                    acc[2][nf] = __builtin_amdgcn_mfma_f32_16x16x32_bf16(a2, bb, acc[2][nf], 0, 0, 0);
                    acc[3][nf] = __builtin_amdgcn_mfma_f32_16x16x32_bf16(a3, bb, acc[3][nf], 0, 0, 0);
                }
            }
        }
        __syncthreads();                      // next buffer staged + this buffer free
        cur ^= 1;
    }

    const int pix0 = (rp * 4 + wn * 2) * 56;
#pragma unroll
    for (int m = 0; m < 4; ++m) {
#pragma unroll
        for (int i = 0; i < 4; ++i) {
            int cout = coutb + m * 16 + l4 * 4 + i;
            float bbv = aggb[b * COUTC + cout];
            float* op = out + ((size_t)(b * COUTC + cout) * NPIX + pix0 + l15);
#pragma unroll
            for (int nf = 0; nf < 7; ++nf) op[nf * 16] = acc[m][nf][i] + bbv;
        }
    }
}

extern "C" void kernel_launch(void* const* d_in, const int* in_sizes, int n_in,
                              void* d_out, int out_size, void* d_ws, size_t ws_size,
                              hipStream_t stream) {
    (void)in_sizes; (void)n_in; (void)out_size; (void)ws_size;
    const float* ref    = (const float*)d_in[0];
    const float* x      = (const float*)d_in[1];
    const float* fc1w   = (const float*)d_in[2];
    const float* fc2w   = (const float*)d_in[3];
    const float* fc2b   = (const float*)d_in[4];
    const float* weight = (const float*)d_in[5];
    const float* bias   = (const float*)d_in[6];
    float* out = (float*)d_out;
    char* ws = (char*)d_ws;

    float*  attn   = (float*)(ws + WS_ATTN);
    float*  aggb   = (float*)(ws + WS_AGGB);
    float*  pooled = (float*)(ws + WS_POOL);
    __bf16* aggw   = (__bf16*)(ws + WS_AGGW);
    __bf16* xpad   = (__bf16*)(ws + WS_XPAD);

    pool_k<<<1024, 256, 0, stream>>>(ref, pooled);
    attn_k<<<1, 256, 0, stream>>>(pooled, fc1w, fc2w, fc2b, attn);
    aggb_k<<<16, 256, 0, stream>>>(attn, bias, aggb);
    aggw_k<<<256, 256, 0, stream>>>(attn, weight, aggw);
    xpad_int_k<<<dim3(49, 4, 16), 256, 0, stream>>>(x, xpad);
    xpad_bor_k<<<3648, 256, 0, stream>>>(xpad);
    conv_k<<<dim3(14, 2, 16), 256, 0, stream>>>(xpad, aggw, aggb, out);
}